// Round 2
// baseline (1584.355 us; speedup 1.0000x reference)
//
#include <hip/hip_runtime.h>
#include <math.h>

#define N_NODES 25000
#define N_EDGES 400000
#define IDEG 0.25f                       // (E/N)^-0.5 = 16^-0.5
#define SQRT3F 1.7320508075688772f
#define INV_SQRT3F 0.5773502691896258f
#define INV_SQRT2F 0.7071067811865476f
#define SCAN_NBLK 25                     // ceil(25000/1024)

__device__ __forceinline__ float silu_f(float x) {
  return x / (1.0f + __expf(-x));
}

// ---------------------------------------------------------------- edge precompute
__global__ __launch_bounds__(256) void edge_pre_k(
    const int* __restrict__ ei, const float* __restrict__ evec,
    float* __restrict__ remb, float* __restrict__ sh1, int* __restrict__ deg) {
  int e = blockIdx.x * 256 + threadIdx.x;
  if (e >= N_EDGES) return;
  float x = evec[3*e+0], y = evec[3*e+1], z = evec[3*e+2];
  float r = sqrtf(x*x + y*y + z*z);
  float inv_r = 1.0f / r;
  sh1[3*e+0] = SQRT3F * x * inv_r;
  sh1[3*e+1] = SQRT3F * y * inv_r;
  sh1[3*e+2] = SQRT3F * z * inv_r;
  float xr = r * 0.25f;                 // r / R_MAX
  float xc = fminf(xr, 1.0f);
  float xc2 = xc*xc, xc3 = xc2*xc, xc6 = xc3*xc3, xc7 = xc6*xc, xc8 = xc7*xc;
  float env = 1.0f - 28.0f*xc6 + 48.0f*xc7 - 21.0f*xc8;   // p=6 polynomial cutoff
  env = (xr < 1.0f) ? env : 0.0f;
  float coef = 0.7071067811865476f * env * inv_r;         // sqrt(2/R_MAX)=sqrt(.5)
  float wv = 0.7853981633974483f * r;                     // pi/R_MAX * r
  // sin(n*wv) by Chebyshev recurrence: 2 trig calls instead of 8
  float s1 = sinf(wv), c1 = cosf(wv);
  float twoc = 2.0f * c1;
  float sp = 0.0f, sc = s1;
  #pragma unroll
  for (int n = 1; n <= 8; ++n) {
    remb[e*8 + n - 1] = coef * sc;
    float sn = twoc * sc - sp;
    sp = sc; sc = sn;
  }
  atomicAdd(&deg[ei[N_EDGES + e]], 1);
}

// ---------------------------------------------------------------- CSR build (3-kernel scan)
__global__ __launch_bounds__(1024) void scanA_k(
    const int* __restrict__ deg, int* __restrict__ rp, int* __restrict__ part) {
  __shared__ int sm[1024];
  int tid = threadIdx.x;
  int idx = blockIdx.x * 1024 + tid;
  int v = (idx < N_NODES) ? deg[idx] : 0;
  sm[tid] = v;
  __syncthreads();
  for (int off = 1; off < 1024; off <<= 1) {
    int t = (tid >= off) ? sm[tid - off] : 0;
    __syncthreads();
    sm[tid] += t;
    __syncthreads();
  }
  if (idx < N_NODES) rp[idx + 1] = sm[tid];
  if (tid == 1023) part[blockIdx.x] = sm[1023];
}

__global__ void scanB_k(int* __restrict__ part) {
  if (threadIdx.x == 0) {
    int acc = 0;
    for (int b = 0; b < SCAN_NBLK; ++b) { int t = part[b]; part[b] = acc; acc += t; }
  }
}

__global__ __launch_bounds__(1024) void scanC_k(
    const int* __restrict__ deg, int* __restrict__ rp, int* __restrict__ cursor,
    const int* __restrict__ part) {
  int idx = blockIdx.x * 1024 + threadIdx.x;
  if (idx >= N_NODES) return;
  int incl = rp[idx + 1] + part[blockIdx.x];
  rp[idx + 1] = incl;
  cursor[idx] = incl - deg[idx];
  if (idx == 0) rp[0] = 0;
}

__global__ __launch_bounds__(256) void scatter_k(
    const int* __restrict__ ei, int* __restrict__ cursor, int* __restrict__ seid) {
  int e = blockIdx.x * 256 + threadIdx.x;
  if (e >= N_EDGES) return;
  int d = ei[N_EDGES + e];
  int pos = atomicAdd(&cursor[d], 1);
  seid[pos] = e;
}

// ---------------------------------------------------------------- layer 0 (fused)
__global__ __launch_bounds__(64) void layer0_k(
    const int* __restrict__ ei, const int* __restrict__ rp, const int* __restrict__ seid,
    const float* __restrict__ remb, const float* __restrict__ sh1,
    const float* __restrict__ xfeat,
    const float* __restrict__ w1, const float* __restrict__ b1,
    const float* __restrict__ w2, const float* __restrict__ b2,
    const float* __restrict__ ws0, const float* __restrict__ wv0,
    float* __restrict__ sinb, float* __restrict__ vb) {
  int n = blockIdx.x;
  int lane = threadIdx.x;
  __shared__ float w1_l[512];
  __shared__ float w2_l[1024];
  __shared__ float h_l[64];
  __shared__ float w_l[16];
  __shared__ float agg_l[32];
  for (int i = lane; i < 512; i += 64) w1_l[i] = w1[i];
  for (int i = lane; i < 1024; i += 64) w2_l[i] = w2[i];
  float b1r = b1[lane];
  int p0 = rp[n], p1 = rp[n+1];
  float acc = 0.0f;
  for (int p = p0; p < p1; ++p) {
    int e = seid[p];
    int src = ei[e];
    float re[8];
    #pragma unroll
    for (int q = 0; q < 8; ++q) re[q] = remb[e*8+q];
    float sx = sh1[3*e], sy = sh1[3*e+1], sz = sh1[3*e+2];
    __syncthreads();                       // protect h_l/w_l from prev iter readers
    float ha = b1r;
    #pragma unroll
    for (int q = 0; q < 8; ++q) ha += re[q] * w1_l[q*64 + lane];
    h_l[lane] = silu_f(ha);
    __syncthreads();
    if (lane < 16) {
      float wa = b2[lane];
      for (int k = 0; k < 64; ++k) wa += h_l[k] * w2_l[k*16 + lane];
      w_l[lane] = wa;
    }
    __syncthreads();
    if (lane < 8) {                        // agg_s[i] += s_e[i]*w_ss[i]
      acc += xfeat[src*8 + lane] * w_l[lane];
    } else if (lane < 32) {                // agg_v[i][d] += s_e[i]*sh1[d]*w_sv[i]
      int c = lane - 8;
      int i = c / 3, d = c - 3*(c/3);
      float sh = (d == 0) ? sx : ((d == 1) ? sy : sz);
      acc += xfeat[src*8 + i] * sh * w_l[8 + i];
    }
  }
  __syncthreads();
  if (lane < 32) agg_l[lane] = acc * IDEG;
  __syncthreads();
  // s = silu(agg_s @ lin0_ws)
  float so = 0.0f;
  #pragma unroll
  for (int m = 0; m < 8; ++m) so += agg_l[m] * ws0[m*64 + lane];
  sinb[n*72 + 8 + lane] = silu_f(so);
  if (lane < 8) sinb[n*72 + lane] = xfeat[n*8 + lane];
  // v[o][d] = sum_m agg_v[m][d] * wv0[m][o]
  for (int pr = lane; pr < 96; pr += 64) {
    int o = pr / 3, d = pr - 3*(pr/3);
    float va = 0.0f;
    #pragma unroll
    for (int m = 0; m < 8; ++m) va += agg_l[8 + m*3 + d] * wv0[m*32 + o];
    vb[n*96 + pr] = va;
  }
}

// ---------------------------------------------------------------- big edge MLP (8->64->240)
// tile = 64 sorted-edge positions; block = 256 (4 waves x 60 output cols); w2 in LDS
__global__ __launch_bounds__(256, 2) void mlp_big_k(
    const int* __restrict__ rp, const int* __restrict__ seid,
    const float* __restrict__ remb,
    const float* __restrict__ w1, const float* __restrict__ b1,
    const float* __restrict__ w2, const float* __restrict__ b2,
    float* __restrict__ wbuf, int nlo, int nhi) {
  __shared__ float w2_l[64*240];          // 60 KiB
  __shared__ float h_l[64*65];            // pitch 65 -> conflict-free reads
  __shared__ float re_l[64*9];
  __shared__ int   eid_l[64];
  int tid = threadIdx.x;
  int plo = rp[nlo], phi = rp[nhi];
  int tp0 = plo + blockIdx.x * 64;
  if (tp0 >= phi) return;                  // uniform per block
  for (int i = tid*4; i < 15360; i += 1024)
    *(float4*)&w2_l[i] = *(const float4*)&w2[i];
  if (tid < 64) {
    int p = tp0 + tid;
    eid_l[tid] = seid[p < phi ? p : (phi - 1)];
  }
  __syncthreads();
  {
    int eg = tid >> 2, q2 = (tid & 3) * 2;
    int e = eid_l[eg];
    re_l[eg*9 + q2]     = remb[e*8 + q2];
    re_l[eg*9 + q2 + 1] = remb[e*8 + q2 + 1];
  }
  __syncthreads();
  {
    int eg = tid & 63, kb = (tid >> 6) * 16;
    for (int k = kb; k < kb + 16; ++k) {
      float a = b1[k];
      #pragma unroll
      for (int q = 0; q < 8; ++q) a += re_l[eg*9 + q] * w1[q*64 + k];
      h_l[eg*65 + k] = silu_f(a);
    }
  }
  __syncthreads();
  int lane = tid & 63, j0 = (tid >> 6) * 60;
  float c[60];
  #pragma unroll
  for (int j = 0; j < 60; ++j) c[j] = b2[j0 + j];
  for (int k = 0; k < 64; ++k) {
    float a = h_l[lane*65 + k];
    #pragma unroll
    for (int jj = 0; jj < 15; ++jj) {
      float4 b = *(const float4*)&w2_l[k*240 + j0 + jj*4];   // same-addr LDS broadcast
      c[jj*4+0] += a * b.x; c[jj*4+1] += a * b.y;
      c[jj*4+2] += a * b.z; c[jj*4+3] += a * b.w;
    }
  }
  float* outp = wbuf + (size_t)(tp0 - plo + lane) * 240 + j0;
  #pragma unroll
  for (int jj = 0; jj < 15; ++jj)
    *(float4*)&outp[jj*4] = make_float4(c[jj*4], c[jj*4+1], c[jj*4+2], c[jj*4+3]);
}

// ---------------------------------------------------------------- layer 1/2 gather (wave per node)
__global__ __launch_bounds__(64) void gather_k(
    const int* __restrict__ ei, const int* __restrict__ rp, const int* __restrict__ seid,
    const float* __restrict__ sh1, const float* __restrict__ wbuf,
    const float* __restrict__ sin_prev, const float* __restrict__ v_prev,
    const float* __restrict__ xfeat,
    const float* __restrict__ ls, const float* __restrict__ lv,
    float* __restrict__ sin_out, float* __restrict__ v_out, int nlo) {
  int n = nlo + blockIdx.x;
  int lane = threadIdx.x;
  __shared__ float w_l[240];
  __shared__ float se_l[72];
  __shared__ float ve_l[96];
  __shared__ float agg_l[512];
  int p0 = rp[n], p1 = rp[n+1];
  int plo = rp[nlo];
  float acc0=0,acc1=0,acc2=0,acc3=0,acc4=0,acc5=0,acc6=0,acc7=0;
  for (int p = p0; p < p1; ++p) {
    int e = seid[p];
    int src = ei[e];
    const float* wrow = wbuf + (size_t)(p - plo) * 240;
    float sx = sh1[3*e], sy = sh1[3*e+1], sz = sh1[3*e+2];
    __syncthreads();                       // protect LDS from prev-iter readers
    w_l[lane]      = wrow[lane];
    w_l[64+lane]   = wrow[64+lane];
    w_l[128+lane]  = wrow[128+lane];
    if (lane < 48) w_l[192+lane] = wrow[192+lane];
    se_l[lane] = sin_prev[(size_t)src*72 + lane];
    if (lane < 8)  se_l[64+lane] = sin_prev[(size_t)src*72 + 64 + lane];
    ve_l[lane] = v_prev[(size_t)src*96 + lane];
    if (lane < 32) ve_l[64+lane] = v_prev[(size_t)src*96 + 64 + lane];
    __syncthreads();
    // flat accumulator f = lane + 64*t over [A:72 | B:32 | C:216 | D:96 | E:96]
    acc0 += se_l[lane] * w_l[lane];                              // t=0: A
    {                                                            // t=1: A/B/C
      int f = 64 + lane;
      float m;
      if (f < 72) m = se_l[f] * w_l[f];
      else if (f < 104) {
        int i = f - 72;
        float dot = (ve_l[i*3]*sx + ve_l[i*3+1]*sy + ve_l[i*3+2]*sz) * INV_SQRT3F;
        m = dot * w_l[72 + i];
      } else {
        int cc = f - 104; int j = cc/3, d = cc - 3*(cc/3);
        float sh = (d==0) ? sx : ((d==1) ? sy : sz);
        m = se_l[j] * sh * w_l[104 + j];
      }
      acc1 += m;
    }
    #pragma unroll
    for (int t = 2; t <= 4; ++t) {                               // t=2..4: C
      int cc = 64*t + lane - 104;
      int j = cc/3, d = cc - 3*(cc/3);
      float sh = (d==0) ? sx : ((d==1) ? sy : sz);
      float m = se_l[j] * sh * w_l[104 + j];
      if (t == 2) acc2 += m; else if (t == 3) acc3 += m; else acc4 += m;
    }
    acc5 += ve_l[lane] * w_l[176 + lane/3];                      // t=5: D
    {                                                            // t=6: D/E
      if (lane < 32) {
        int cc = 64 + lane;
        acc6 += ve_l[cc] * w_l[176 + cc/3];
      } else {
        int cc = lane - 32; int i = cc/3, d = cc - 3*(cc/3);
        float a0 = ve_l[i*3], a1 = ve_l[i*3+1], a2 = ve_l[i*3+2];
        float cr = (d==0) ? (a1*sz - a2*sy) : ((d==1) ? (a2*sx - a0*sz) : (a0*sy - a1*sx));
        acc6 += cr * INV_SQRT2F * w_l[208 + i];
      }
    }
    {                                                            // t=7: E
      int cc = 32 + lane; int i = cc/3, d = cc - 3*(cc/3);
      float a0 = ve_l[i*3], a1 = ve_l[i*3+1], a2 = ve_l[i*3+2];
      float cr = (d==0) ? (a1*sz - a2*sy) : ((d==1) ? (a2*sx - a0*sz) : (a0*sy - a1*sx));
      acc7 += cr * INV_SQRT2F * w_l[208 + i];
    }
  }
  __syncthreads();
  agg_l[lane]       = acc0 * IDEG;
  agg_l[64 + lane]  = acc1 * IDEG;
  agg_l[128 + lane] = acc2 * IDEG;
  agg_l[192 + lane] = acc3 * IDEG;
  agg_l[256 + lane] = acc4 * IDEG;
  agg_l[320 + lane] = acc5 * IDEG;
  agg_l[384 + lane] = acc6 * IDEG;
  agg_l[448 + lane] = acc7 * IDEG;
  __syncthreads();
  // s_new = s_old + silu(agg_s @ ls)
  float so = 0.0f;
  for (int m = 0; m < 104; ++m) so += agg_l[m] * ls[m*64 + lane];
  sin_out[(size_t)n*72 + 8 + lane] = sin_prev[(size_t)n*72 + 8 + lane] + silu_f(so);
  if (lane < 8) sin_out[(size_t)n*72 + lane] = xfeat[n*8 + lane];
  // v_new = v_old + sum_m agg_v[m][d] * lv[m][o]   (agg_v[m][d] = agg_l[104+3m+d])
  for (int pr = lane; pr < 96; pr += 64) {
    int o = pr / 3, d = pr - 3*(pr/3);
    float va = 0.0f;
    for (int m = 0; m < 136; ++m) va += agg_l[104 + m*3 + d] * lv[m*32 + o];
    v_out[(size_t)n*96 + pr] = v_prev[(size_t)n*96 + pr] + va;
  }
}

// ---------------------------------------------------------------- readout
__global__ __launch_bounds__(64) void readout_k(
    const float* __restrict__ sinb, const float* __restrict__ vb,
    const int* __restrict__ ptype, const float* __restrict__ row,
    const float* __restrict__ rob, float* __restrict__ out) {
  int n = blockIdx.x;
  int lane = threadIdx.x;
  __shared__ float f_l[96];
  f_l[lane] = sinb[(size_t)n*72 + 8 + lane];
  if (lane < 32) {
    float a = vb[(size_t)n*96 + lane*3];
    float b = vb[(size_t)n*96 + lane*3 + 1];
    float c = vb[(size_t)n*96 + lane*3 + 2];
    f_l[64 + lane] = sqrtf(a*a + b*b + c*c + 1e-12f);
  }
  __syncthreads();
  if (lane < 10) {
    int pt = ptype[n];
    const float* wr = row + pt * 960;
    float acc = rob[pt*10 + lane];
    for (int j = 0; j < 96; ++j) acc += f_l[j] * wr[j*10 + lane];
    out[n*10 + lane] = acc;
  }
}

// ---------------------------------------------------------------- launch
extern "C" void kernel_launch(void* const* d_in, const int* in_sizes, int n_in,
                              void* d_out, int out_size, void* d_ws, size_t ws_size,
                              hipStream_t stream) {
  (void)in_sizes; (void)n_in; (void)out_size;
  const float* xfeat = (const float*)d_in[0];
  const int*   ptype = (const int*)d_in[1];
  const int*   ei    = (const int*)d_in[2];
  const float* evec  = (const float*)d_in[3];
  const float* m0w1  = (const float*)d_in[4];
  const float* m0b1  = (const float*)d_in[5];
  const float* m0w2  = (const float*)d_in[6];
  const float* m0b2  = (const float*)d_in[7];
  const float* l0ws  = (const float*)d_in[8];
  const float* l0wv  = (const float*)d_in[9];
  const float* mw1[2] = {(const float*)d_in[10], (const float*)d_in[16]};
  const float* mb1[2] = {(const float*)d_in[11], (const float*)d_in[17]};
  const float* mw2[2] = {(const float*)d_in[12], (const float*)d_in[18]};
  const float* mb2[2] = {(const float*)d_in[13], (const float*)d_in[19]};
  const float* lws[2] = {(const float*)d_in[14], (const float*)d_in[20]};
  const float* lwv[2] = {(const float*)d_in[15], (const float*)d_in[21]};
  const float* row   = (const float*)d_in[22];
  const float* rob   = (const float*)d_in[23];
  float* out = (float*)d_out;

  float* ws   = (float*)d_ws;
  float* remb = ws;                                   // E*8
  float* sh1  = remb + (size_t)N_EDGES*8;             // E*3
  float* sin0 = sh1  + (size_t)N_EDGES*3;             // N*72
  float* sin1 = sin0 + (size_t)N_NODES*72;            // N*72
  float* v0   = sin1 + (size_t)N_NODES*72;            // N*96
  float* v1   = v0   + (size_t)N_NODES*96;            // N*96
  int* deg    = (int*)(v1 + (size_t)N_NODES*96);      // N
  int* rp     = deg + N_NODES;                        // N+1
  int* cursor = rp + N_NODES + 1;                     // N
  int* part   = cursor + N_NODES;                     // 32 (scan partials)
  int* seid   = part + 32;                            // E (+3 pad -> wbuf 16B-aligned)
  float* wbuf = (float*)(seid + N_EDGES + 3);

  size_t fixed = (size_t)(wbuf - ws);
  size_t avail = (ws_size / 4 > fixed) ? (ws_size / 4 - fixed) : 0;
  int NC = 1;
  while (NC < 1024 && (size_t)(N_EDGES / NC + 8256) * 240 > avail) NC <<= 1;
  int cap = N_EDGES / NC + 8192;

  hipMemsetAsync(deg, 0, N_NODES * sizeof(int), stream);
  edge_pre_k<<<(N_EDGES + 255) / 256, 256, 0, stream>>>(ei, evec, remb, sh1, deg);
  scanA_k<<<SCAN_NBLK, 1024, 0, stream>>>(deg, rp, part);
  scanB_k<<<1, 64, 0, stream>>>(part);
  scanC_k<<<SCAN_NBLK, 1024, 0, stream>>>(deg, rp, cursor, part);
  scatter_k<<<(N_EDGES + 255) / 256, 256, 0, stream>>>(ei, cursor, seid);
  layer0_k<<<N_NODES, 64, 0, stream>>>(ei, rp, seid, remb, sh1, xfeat,
      m0w1, m0b1, m0w2, m0b2, l0ws, l0wv, sin0, v0);

  const float* sin_in = sin0; const float* v_in = v0;
  float* sin_out = sin1; float* v_out = v1;
  for (int l = 0; l < 2; ++l) {
    for (int c = 0; c < NC; ++c) {
      int nlo = (int)((long long)N_NODES * c / NC);
      int nhi = (int)((long long)N_NODES * (c + 1) / NC);
      mlp_big_k<<<(cap + 63) / 64, 256, 0, stream>>>(rp, seid, remb,
          mw1[l], mb1[l], mw2[l], mb2[l], wbuf, nlo, nhi);
      gather_k<<<nhi - nlo, 64, 0, stream>>>(ei, rp, seid, sh1, wbuf,
          sin_in, v_in, xfeat, lws[l], lwv[l], sin_out, v_out, nlo);
    }
    const float* t;
    t = sin_in; sin_in = sin_out; sin_out = (float*)t;
    t = v_in;   v_in = v_out;     v_out = (float*)t;
  }
  readout_k<<<N_NODES, 64, 0, stream>>>(sin_in, v_in, ptype, row, rob, out);
}